// Round 1
// baseline (276.260 us; speedup 1.0000x reference)
//
#include <hip/hip_runtime.h>
#include <hip/hip_bf16.h>
#include <cmath>
#include <stdint.h>

#define B_ 8
#define T_ 2048
#define C_ 1024
#define HS_ 64
#define NS 8           // key splits per q-tile
#define LP 72          // attn LDS row stride in shorts

typedef __attribute__((ext_vector_type(8))) short short8;    // 8 bf16 (4 VGPRs) - MFMA A/B frag
typedef __attribute__((ext_vector_type(4))) float floatx4;   // MFMA C/D frag

__device__ inline unsigned short f2bf(float f) {
    union { float f; unsigned u; } v; v.f = f;
    unsigned r = v.u + 0x7FFF + ((v.u >> 16) & 1);   // RNE
    return (unsigned short)(r >> 16);
}
__device__ inline unsigned pk2bf(float a, float b) {   // -> v_cvt_pk_bf16_f32
    union { __hip_bfloat162 h; unsigned u; } v;
    v.h = __float22bfloat162_rn(float2{a, b});
    return v.u;
}
__device__ inline float bf2f(unsigned short u) {
    union { unsigned u; float f; } w; w.u = ((unsigned)u) << 16; return w.f;
}

// ---------------------------------------------------------------------------
// Kernel 1: W [C x HS] fp32  ->  W^T [HS x C] bf16  (3 matrices)
// ---------------------------------------------------------------------------
__global__ __launch_bounds__(256) void prep_wt(const float* __restrict__ Wq,
                                               const float* __restrict__ Wk,
                                               const float* __restrict__ Wv,
                                               unsigned short* __restrict__ wt) {
    int p = blockIdx.x >> 4;
    int chunk = blockIdx.x & 15;
    const float* W = (p == 0) ? Wq : (p == 1) ? Wk : Wv;
    unsigned short* WT = wt + p * (C_ * HS_);
    int base = chunk * 4096;
    for (int i = threadIdx.x; i < 4096; i += 256) {
        int idx = base + i;
        int k = idx >> 6, n = idx & 63;
        WT[n * C_ + k] = f2bf(W[idx]);
    }
}

// ---------------------------------------------------------------------------
// Kernel 2: projections. X [16384x1024] fp32 @ W [1024x64] -> bf16 [16384x64]
//
// Rewritten barrier-free / LDS-free: each WAVE independently owns a 16-row
// tile and runs the full K=1024 reduction. A-frags are built in-register
// from direct fp32 global loads (lane l16 = row, 8 contiguous floats at
// quad*8) via v_cvt_pk_bf16_f32. B-frags are loaded directly from WT
// (row-major [n][k] means short8 at (nt*16+l16)*C + k0 + quad*8 IS the
// fragment) — WT is 128 KB, L2-resident across 1024 waves.
// No __syncthreads anywhere; register double-buffer (depth 1) + 12
// independent waves/CU keeps ~70 KB of loads in flight per CU, far above
// the ~9 KB BW-latency product -> HBM-bound.
// grid = 768 (3 proj x 1024 wave-tiles / 4 waves per block), block = 256.
// ---------------------------------------------------------------------------
__global__ __launch_bounds__(256) void proj_kernel(
    const float* __restrict__ qv, const float* __restrict__ kv, const float* __restrict__ vv,
    const unsigned short* __restrict__ wt,
    unsigned short* __restrict__ qb, unsigned short* __restrict__ kb, unsigned short* __restrict__ vb)
{
    const int tid  = threadIdx.x;
    const int wave = tid >> 6, lane = tid & 63, quad = lane >> 4, l16 = lane & 15;
    const int wid  = blockIdx.x * 4 + wave;     // 0..3071
    const int p    = wid >> 10;                 // projection: 1024 tiles each
    const int tile = wid & 1023;                // 16-row tile index

    const float* X = (p == 0) ? qv : (p == 1) ? kv : vv;
    const unsigned short* WT = wt + p * (C_ * HS_);
    unsigned short* Ob = (p == 0) ? qb : (p == 1) ? kb : vb;
    const float oscale = (p == 0) ? 0.125f : 1.0f;   // fold HS^-0.5 into Q

    const float* xp = X + ((long)tile * 16 + l16) * C_ + quad * 8;
    const unsigned short* wp = WT + l16 * C_ + quad * 8;

    floatx4 acc[4] = { {0,0,0,0},{0,0,0,0},{0,0,0,0},{0,0,0,0} };

    // register double-buffer, depth 1
    floatx4 xa, xb;
    short8 bfr0, bfr1, bfr2, bfr3;
    xa = *(const floatx4*)(xp);
    xb = *(const floatx4*)(xp + 4);
    bfr0 = *(const short8*)(wp + 0 * 16 * C_);
    bfr1 = *(const short8*)(wp + 1 * 16 * C_);
    bfr2 = *(const short8*)(wp + 2 * 16 * C_);
    bfr3 = *(const short8*)(wp + 3 * 16 * C_);

    #pragma unroll 4
    for (int ks = 0; ks < 32; ++ks) {
        floatx4 cx0 = xa, cx1 = xb;
        short8 cb0 = bfr0, cb1 = bfr1, cb2 = bfr2, cb3 = bfr3;
        if (ks + 1 < 32) {
            const int k0 = (ks + 1) * 32;
            xa = *(const floatx4*)(xp + k0);
            xb = *(const floatx4*)(xp + k0 + 4);
            bfr0 = *(const short8*)(wp + 0 * 16 * C_ + k0);
            bfr1 = *(const short8*)(wp + 1 * 16 * C_ + k0);
            bfr2 = *(const short8*)(wp + 2 * 16 * C_ + k0);
            bfr3 = *(const short8*)(wp + 3 * 16 * C_ + k0);
        }
        union { short8 s; unsigned u[4]; } af;
        af.u[0] = pk2bf(cx0[0], cx0[1]);
        af.u[1] = pk2bf(cx0[2], cx0[3]);
        af.u[2] = pk2bf(cx1[0], cx1[1]);
        af.u[3] = pk2bf(cx1[2], cx1[3]);
        acc[0] = __builtin_amdgcn_mfma_f32_16x16x32_bf16(af.s, cb0, acc[0], 0, 0, 0);
        acc[1] = __builtin_amdgcn_mfma_f32_16x16x32_bf16(af.s, cb1, acc[1], 0, 0, 0);
        acc[2] = __builtin_amdgcn_mfma_f32_16x16x32_bf16(af.s, cb2, acc[2], 0, 0, 0);
        acc[3] = __builtin_amdgcn_mfma_f32_16x16x32_bf16(af.s, cb3, acc[3], 0, 0, 0);
    }

    // C layout: row = tile*16 + quad*4 + r, col = nt*16 + l16
    unsigned short* op = Ob + ((long)tile * 16 + quad * 4) * HS_ + l16;
    #pragma unroll
    for (int nt = 0; nt < 4; ++nt)
        #pragma unroll
        for (int r = 0; r < 4; ++r)
            op[r * HS_ + nt * 16] = f2bf(acc[nt][r] * oscale);
}

// ---------------------------------------------------------------------------
// Kernel 3a: flash attention partials with key-split.
// grid = 8b x 32qt x NS splits = 2048 WGs, block = 256 (4 waves x 16 q-rows).
// ---------------------------------------------------------------------------
__global__ __launch_bounds__(256) void attn_partial(
    const unsigned short* __restrict__ qb, const unsigned short* __restrict__ kb,
    const unsigned short* __restrict__ vb, const int* __restrict__ mask,
    unsigned short* __restrict__ Opart, float* __restrict__ Mpart, float* __restrict__ Lpart)
{
    const int s  = blockIdx.x & (NS - 1);
    const int bq = blockIdx.x >> 3;          // b*32 + qt
    const int qt = bq & 31;
    const int b  = bq >> 5;
    if (s > qt) return;                       // empty split; combine skips it

    __shared__ unsigned short Klds[64 * LP];      // K chunk [key][feat]
    __shared__ unsigned short Vt[64 * LP];        // V chunk transposed [feat][key]
    __shared__ unsigned short Plds[4][16 * LP];   // per-wave P scratch [qrow][key]

    const int tid = threadIdx.x;
    const int wave = tid >> 6, lane = tid & 63, quad = lane >> 4, l16 = lane & 15;

    // Q fragments (A-operand: m = l16, k = quad*8+j); scale folded in.
    const int qrow = qt * 64 + wave * 16 + l16;
    const unsigned short* qp = qb + ((long)(b * T_ + qrow)) * HS_;
    short8 aq0 = *(const short8*)&qp[0  + quad * 8];
    short8 aq1 = *(const short8*)&qp[32 + quad * 8];

    floatx4 acc_o[4] = { {0,0,0,0},{0,0,0,0},{0,0,0,0},{0,0,0,0} };
    float m_r[4] = { -INFINITY, -INFINITY, -INFINITY, -INFINITY };
    float l_r[4] = { 0.f, 0.f, 0.f, 0.f };

    const int rowg = qt * 64 + wave * 16 + quad * 4;

    const int skey = tid >> 3;
    const int sf8  = (tid & 7) * 8;
    const int vp = tid & 31, vg = tid >> 5;

    for (int c = s; c <= qt; c += NS) {
        const int kc = c * 64;
        #pragma unroll
        for (int it = 0; it < 2; ++it) {
            int key = it * 32 + skey;
            *(short8*)&Klds[key * LP + sf8] =
                *(const short8*)&kb[((long)(b * T_ + kc + key)) * HS_ + sf8];
        }
        {
            const unsigned short* v0p = &vb[((long)(b * T_ + kc + 2 * vp)) * HS_ + vg * 8];
            short8 v0 = *(const short8*)v0p;
            short8 v1 = *(const short8*)(v0p + HS_);
            #pragma unroll
            for (int j = 0; j < 8; ++j) {
                unsigned pr = (unsigned)(unsigned short)v0[j] |
                              ((unsigned)(unsigned short)v1[j] << 16);
                *(unsigned*)&Vt[(vg * 8 + j) * LP + 2 * vp] = pr;
            }
        }
        __syncthreads();

        floatx4 sv[4];
        #pragma unroll
        for (int kt = 0; kt < 4; ++kt) {
            floatx4 a = {0.f, 0.f, 0.f, 0.f};
            short8 bk0 = *(short8*)&Klds[(kt * 16 + l16) * LP + 0  + quad * 8];
            short8 bk1 = *(short8*)&Klds[(kt * 16 + l16) * LP + 32 + quad * 8];
            a = __builtin_amdgcn_mfma_f32_16x16x32_bf16(aq0, bk0, a, 0, 0, 0);
            a = __builtin_amdgcn_mfma_f32_16x16x32_bf16(aq1, bk1, a, 0, 0, 0);
            sv[kt] = a;
        }

        const bool lastc = (c == qt);
        #pragma unroll
        for (int kt = 0; kt < 4; ++kt) {
            int key = kc + kt * 16 + l16;
            int mk = mask[b * T_ + key];
            #pragma unroll
            for (int r = 0; r < 4; ++r) {
                bool dead = (mk == 0) || (lastc && key > rowg + r);
                if (dead) sv[kt][r] = -INFINITY;
            }
        }

        float alpha[4];
        #pragma unroll
        for (int r = 0; r < 4; ++r) {
            float mx = fmaxf(fmaxf(sv[0][r], sv[1][r]), fmaxf(sv[2][r], sv[3][r]));
            #pragma unroll
            for (int off = 1; off < 16; off <<= 1)
                mx = fmaxf(mx, __shfl_xor(mx, off));
            float mn = fmaxf(m_r[r], mx);
            float a_ = __expf(m_r[r] - mn);
            float ps = 0.f;
            #pragma unroll
            for (int kt = 0; kt < 4; ++kt) {
                float pv = __expf(sv[kt][r] - mn);
                sv[kt][r] = pv;
                ps += pv;
            }
            #pragma unroll
            for (int off = 1; off < 16; off <<= 1)
                ps += __shfl_xor(ps, off);
            l_r[r] = l_r[r] * a_ + ps;
            m_r[r] = mn;
            alpha[r] = a_;
        }
        #pragma unroll
        for (int nt = 0; nt < 4; ++nt)
            #pragma unroll
            for (int r = 0; r < 4; ++r)
                acc_o[nt][r] *= alpha[r];

        unsigned short* pl = Plds[wave];
        #pragma unroll
        for (int kt = 0; kt < 4; ++kt)
            #pragma unroll
            for (int r = 0; r < 4; ++r)
                pl[(quad * 4 + r) * LP + kt * 16 + l16] = f2bf(sv[kt][r]);
        short8 ap0 = *(short8*)&pl[l16 * LP + 0  + quad * 8];
        short8 ap1 = *(short8*)&pl[l16 * LP + 32 + quad * 8];

        #pragma unroll
        for (int nt = 0; nt < 4; ++nt) {
            short8 bv0 = *(short8*)&Vt[(nt * 16 + l16) * LP + 0  + quad * 8];
            short8 bv1 = *(short8*)&Vt[(nt * 16 + l16) * LP + 32 + quad * 8];
            acc_o[nt] = __builtin_amdgcn_mfma_f32_16x16x32_bf16(ap0, bv0, acc_o[nt], 0, 0, 0);
            acc_o[nt] = __builtin_amdgcn_mfma_f32_16x16x32_bf16(ap1, bv1, acc_o[nt], 0, 0, 0);
        }
        __syncthreads();
    }

    // write partials: O unnormalized (bf16), m/l fp32
    unsigned short* Op = Opart + (long)blockIdx.x * 4096;
    #pragma unroll
    for (int nt = 0; nt < 4; ++nt)
        #pragma unroll
        for (int r = 0; r < 4; ++r)
            Op[(wave * 16 + quad * 4 + r) * 64 + nt * 16 + l16] = f2bf(acc_o[nt][r]);
    if (l16 == 0) {
        #pragma unroll
        for (int r = 0; r < 4; ++r) {
            int rl = wave * 16 + quad * 4 + r;
            Mpart[(long)blockIdx.x * 64 + rl] = m_r[r];
            Lpart[(long)blockIdx.x * 64 + rl] = l_r[r];
        }
    }
}

// ---------------------------------------------------------------------------
// Kernel 3b: combine split partials. grid = 8b x 32qt x 2 = 512, block = 256.
// ---------------------------------------------------------------------------
__global__ __launch_bounds__(256) void attn_combine(
    const unsigned short* __restrict__ Opart, const float* __restrict__ Mpart,
    const float* __restrict__ Lpart, float* __restrict__ out)
{
    const int half = blockIdx.x & 1;
    const int bq = blockIdx.x >> 1;
    const int qt = bq & 31;
    const int b  = bq >> 5;
    const int nsp = (qt + 1 < NS) ? qt + 1 : NS;

    const int row  = (threadIdx.x >> 3) + half * 32;   // 0..63
    const int colg = (threadIdx.x & 7) * 8;
    const long base = (long)bq * NS;

    float M = -INFINITY;
    #pragma unroll
    for (int sp = 0; sp < NS; ++sp)
        if (sp < nsp) M = fmaxf(M, Mpart[(base + sp) * 64 + row]);

    float w[NS];
    float L = 0.f;
    #pragma unroll
    for (int sp = 0; sp < NS; ++sp)
        if (sp < nsp) {
            float e = __expf(Mpart[(base + sp) * 64 + row] - M);
            w[sp] = e;
            L += e * Lpart[(base + sp) * 64 + row];
        }

    float acc[8] = {0,0,0,0,0,0,0,0};
    #pragma unroll
    for (int sp = 0; sp < NS; ++sp)
        if (sp < nsp) {
            const unsigned short* Op = Opart + (base + sp) * 4096 + row * 64 + colg;
            short8 o = *(const short8*)Op;
            float ws = w[sp];
            #pragma unroll
            for (int j = 0; j < 8; ++j)
                acc[j] += ws * bf2f((unsigned short)o[j]);
        }

    float inv = 1.0f / L;
    float* op = out + ((long)(b * T_ + qt * 64 + row)) * HS_ + colg;
    floatx4 o0 = { acc[0] * inv, acc[1] * inv, acc[2] * inv, acc[3] * inv };
    floatx4 o1 = { acc[4] * inv, acc[5] * inv, acc[6] * inv, acc[7] * inv };
    *(floatx4*)op = o0;
    *(floatx4*)(op + 4) = o1;
}

// ---------------------------------------------------------------------------
extern "C" void kernel_launch(void* const* d_in, const int* in_sizes, int n_in,
                              void* d_out, int out_size, void* d_ws, size_t ws_size,
                              hipStream_t stream)
{
    const float* qv = (const float*)d_in[0];
    const float* kv = (const float*)d_in[1];
    const float* vv = (const float*)d_in[2];
    const int*   mask = (const int*)d_in[3];
    const float* Wq = (const float*)d_in[4];
    const float* Wk = (const float*)d_in[5];
    const float* Wv = (const float*)d_in[6];
    float* out = (float*)d_out;

    // ws layout: W^T x3 | q/k/v bf16 | O partials bf16 | M,L fp32  (~24.2 MB)
    unsigned short* wt    = (unsigned short*)d_ws;
    unsigned short* qbuf  = wt + 3 * C_ * HS_;
    unsigned short* kbuf  = qbuf + (long)B_ * T_ * HS_;
    unsigned short* vbuf  = kbuf + (long)B_ * T_ * HS_;
    unsigned short* Opart = vbuf + (long)B_ * T_ * HS_;
    float* Mpart = (float*)(Opart + (long)B_ * 32 * NS * 4096);
    float* Lpart = Mpart + (long)B_ * 32 * NS * 64;

    prep_wt<<<48, 256, 0, stream>>>(Wq, Wk, Wv, wt);
    proj_kernel<<<768, 256, 0, stream>>>(qv, kv, vv, wt, qbuf, kbuf, vbuf);
    attn_partial<<<B_ * 32 * NS, 256, 0, stream>>>(qbuf, kbuf, vbuf, mask, Opart, Mpart, Lpart);
    attn_combine<<<B_ * 32 * 2, 256, 0, stream>>>(Opart, Mpart, Lpart, out);
}

// Round 2
// 260.769 us; speedup vs baseline: 1.0594x; 1.0594x over previous
//
#include <hip/hip_runtime.h>
#include <hip/hip_bf16.h>
#include <cmath>
#include <stdint.h>

#define B_ 8
#define T_ 2048
#define C_ 1024
#define HS_ 64
#define NS 8           // key splits per q-tile
#define LP 72          // attn LDS row stride in shorts
#define PLP 520        // proj W LDS row stride in shorts (512 + 8 pad -> stride = 4 dwords mod 32, balanced b128)

typedef __attribute__((ext_vector_type(8))) short short8;    // 8 bf16 (4 VGPRs) - MFMA A/B frag
typedef __attribute__((ext_vector_type(4))) float floatx4;   // MFMA C/D frag

__device__ inline unsigned short f2bf(float f) {
    union { float f; unsigned u; } v; v.f = f;
    unsigned r = v.u + 0x7FFF + ((v.u >> 16) & 1);   // RNE
    return (unsigned short)(r >> 16);
}
__device__ inline unsigned pk2bf(float a, float b) {   // -> v_cvt_pk_bf16_f32
    union { __hip_bfloat162 h; unsigned u; } v;
    v.h = __float22bfloat162_rn(float2{a, b});
    return v.u;
}
__device__ inline float bf2f(unsigned short u) {
    union { unsigned u; float f; } w; w.u = ((unsigned)u) << 16; return w.f;
}

// ---------------------------------------------------------------------------
// Kernel 1: W [C x HS] fp32  ->  W^T [HS x C] bf16  (3 matrices)
// ---------------------------------------------------------------------------
__global__ __launch_bounds__(256) void prep_wt(const float* __restrict__ Wq,
                                               const float* __restrict__ Wk,
                                               const float* __restrict__ Wv,
                                               unsigned short* __restrict__ wt) {
    int p = blockIdx.x >> 4;
    int chunk = blockIdx.x & 15;
    const float* W = (p == 0) ? Wq : (p == 1) ? Wk : Wv;
    unsigned short* WT = wt + p * (C_ * HS_);
    int base = chunk * 4096;
    for (int i = threadIdx.x; i < 4096; i += 256) {
        int idx = base + i;
        int k = idx >> 6, n = idx & 63;
        WT[n * C_ + k] = f2bf(W[idx]);
    }
}

// ---------------------------------------------------------------------------
// Kernel 2: projections. X [16384x1024] fp32 @ W [1024x64] -> bf16 [16384x64]
//
// Round-2 structure: W^T lives in LDS (staged once per block, coalesced),
// X streamed direct-to-register with depth-2 prefetch. Rationale: round-1's
// direct-from-global B-frags were 2KB-stride scatters (64 lines per wave
// instr) that saturated the memory request queues at ~2.3 TB/s effective
// while every pipe idled. Now the only global stream is X (fully line-used
// loads), W is read from LDS conflict-minimal (row stride 520 shorts = 260
// dwords = 4 mod 32 -> exactly 8 lanes per 4-bank group = the b128 minimum).
// K split in two 512 halves: 65 KB LDS -> 2 blocks/CU; half-1 W preloaded
// into registers during half-0 compute so the boundary restage is latency-
// free. 4 barriers per block total.
// grid = 768 (3 proj x 256 tiles of 64 rows), block = 256 (4 waves).
// ---------------------------------------------------------------------------
__global__ __launch_bounds__(256) void proj_kernel(
    const float* __restrict__ qv, const float* __restrict__ kv, const float* __restrict__ vv,
    const unsigned short* __restrict__ wt,
    unsigned short* __restrict__ qb, unsigned short* __restrict__ kb, unsigned short* __restrict__ vb)
{
    __shared__ unsigned short Wl[64 * PLP];   // 65 KB -> 2 blocks/CU

    const int tid  = threadIdx.x;
    const int wave = tid >> 6, lane = tid & 63, quad = lane >> 4, l16 = lane & 15;
    const int bid  = blockIdx.x;
    const int p    = bid >> 8;                // projection
    const int t64  = bid & 255;               // 64-row tile

    const float* X = (p == 0) ? qv : (p == 1) ? kv : vv;
    const unsigned short* WT = wt + p * (C_ * HS_);
    unsigned short* Ob = (p == 0) ? qb : (p == 1) ? kb : vb;
    const float oscale = (p == 0) ? 0.125f : 1.0f;   // fold HS^-0.5 into Q

    // stage half-0 of W^T (cols 0..511) into LDS, coalesced
    const int srow = (tid >> 6) * 4 + 0;      // recomputed in loop below
    short8 wreg[16];
    #pragma unroll
    for (int it = 0; it < 16; ++it) {
        int u = it * 256 + tid;               // 0..4095 16B-units
        int row = u >> 6, c16 = u & 63;
        wreg[it] = *(const short8*)(WT + row * C_ + c16 * 8);
    }
    #pragma unroll
    for (int it = 0; it < 16; ++it) {
        int u = it * 256 + tid;
        int row = u >> 6, c16 = u & 63;
        *(short8*)&Wl[row * PLP + c16 * 8] = wreg[it];
    }
    __syncthreads();
    (void)srow;

    // preload half-1 of W^T into registers; these loads fly during half-0 compute
    short8 wreg2[16];
    #pragma unroll
    for (int it = 0; it < 16; ++it) {
        int u = it * 256 + tid;
        int row = u >> 6, c16 = u & 63;
        wreg2[it] = *(const short8*)(WT + row * C_ + 512 + c16 * 8);
    }

    // per-wave X row pointer: A-frag lane l16 = row m, quad*8+j = k
    const float* xp = X + ((long)t64 * 64 + wave * 16 + l16) * C_ + quad * 8;

    floatx4 acc[4] = { {0,0,0,0},{0,0,0,0},{0,0,0,0},{0,0,0,0} };

    #pragma unroll
    for (int h = 0; h < 2; ++h) {
        const float* xh = xp + h * 512;
        // depth-2 register prefetch queue for X
        floatx4 x0a = *(const floatx4*)(xh + 0);
        floatx4 x0b = *(const floatx4*)(xh + 4);
        floatx4 x1a = *(const floatx4*)(xh + 32);
        floatx4 x1b = *(const floatx4*)(xh + 36);

        #pragma unroll
        for (int ks = 0; ks < 16; ++ks) {
            floatx4 ca, cb;
            if (ks & 1) { ca = x1a; cb = x1b; } else { ca = x0a; cb = x0b; }
            if (ks + 2 < 16) {
                const float* nx = xh + (ks + 2) * 32;
                if (ks & 1) { x1a = *(const floatx4*)nx; x1b = *(const floatx4*)(nx + 4); }
                else        { x0a = *(const floatx4*)nx; x0b = *(const floatx4*)(nx + 4); }
            }
            union { short8 s; unsigned u[4]; } af;
            af.u[0] = pk2bf(ca[0], ca[1]);
            af.u[1] = pk2bf(ca[2], ca[3]);
            af.u[2] = pk2bf(cb[0], cb[1]);
            af.u[3] = pk2bf(cb[2], cb[3]);

            const unsigned short* wl = &Wl[l16 * PLP + ks * 32 + quad * 8];
            short8 b0 = *(const short8*)(wl + 0 * 16 * PLP);
            short8 b1 = *(const short8*)(wl + 1 * 16 * PLP);
            short8 b2 = *(const short8*)(wl + 2 * 16 * PLP);
            short8 b3 = *(const short8*)(wl + 3 * 16 * PLP);

            acc[0] = __builtin_amdgcn_mfma_f32_16x16x32_bf16(af.s, b0, acc[0], 0, 0, 0);
            acc[1] = __builtin_amdgcn_mfma_f32_16x16x32_bf16(af.s, b1, acc[1], 0, 0, 0);
            acc[2] = __builtin_amdgcn_mfma_f32_16x16x32_bf16(af.s, b2, acc[2], 0, 0, 0);
            acc[3] = __builtin_amdgcn_mfma_f32_16x16x32_bf16(af.s, b3, acc[3], 0, 0, 0);
        }

        if (h == 0) {
            // restage W^T cols 512..1023 from the preloaded registers
            __syncthreads();   // everyone done reading half-0
            #pragma unroll
            for (int it = 0; it < 16; ++it) {
                int u = it * 256 + tid;
                int row = u >> 6, c16 = u & 63;
                *(short8*)&Wl[row * PLP + c16 * 8] = wreg2[it];
            }
            __syncthreads();
        }
    }

    // C layout: row = quad*4 + r (within wave tile), col = nt*16 + l16
    unsigned short* op = Ob + ((long)t64 * 64 + wave * 16 + quad * 4) * HS_ + l16;
    #pragma unroll
    for (int nt = 0; nt < 4; ++nt)
        #pragma unroll
        for (int r = 0; r < 4; ++r)
            op[r * HS_ + nt * 16] = f2bf(acc[nt][r] * oscale);
}

// ---------------------------------------------------------------------------
// Kernel 3a: flash attention partials with key-split.
// grid = 8b x 32qt x NS splits = 2048 WGs, block = 256 (4 waves x 16 q-rows).
// ---------------------------------------------------------------------------
__global__ __launch_bounds__(256) void attn_partial(
    const unsigned short* __restrict__ qb, const unsigned short* __restrict__ kb,
    const unsigned short* __restrict__ vb, const int* __restrict__ mask,
    unsigned short* __restrict__ Opart, float* __restrict__ Mpart, float* __restrict__ Lpart)
{
    const int s  = blockIdx.x & (NS - 1);
    const int bq = blockIdx.x >> 3;          // b*32 + qt
    const int qt = bq & 31;
    const int b  = bq >> 5;
    if (s > qt) return;                       // empty split; combine skips it

    __shared__ unsigned short Klds[64 * LP];      // K chunk [key][feat]
    __shared__ unsigned short Vt[64 * LP];        // V chunk transposed [feat][key]
    __shared__ unsigned short Plds[4][16 * LP];   // per-wave P scratch [qrow][key]

    const int tid = threadIdx.x;
    const int wave = tid >> 6, lane = tid & 63, quad = lane >> 4, l16 = lane & 15;

    // Q fragments (A-operand: m = l16, k = quad*8+j); scale folded in.
    const int qrow = qt * 64 + wave * 16 + l16;
    const unsigned short* qp = qb + ((long)(b * T_ + qrow)) * HS_;
    short8 aq0 = *(const short8*)&qp[0  + quad * 8];
    short8 aq1 = *(const short8*)&qp[32 + quad * 8];

    floatx4 acc_o[4] = { {0,0,0,0},{0,0,0,0},{0,0,0,0},{0,0,0,0} };
    float m_r[4] = { -INFINITY, -INFINITY, -INFINITY, -INFINITY };
    float l_r[4] = { 0.f, 0.f, 0.f, 0.f };

    const int rowg = qt * 64 + wave * 16 + quad * 4;

    const int skey = tid >> 3;
    const int sf8  = (tid & 7) * 8;
    const int vp = tid & 31, vg = tid >> 5;

    for (int c = s; c <= qt; c += NS) {
        const int kc = c * 64;
        #pragma unroll
        for (int it = 0; it < 2; ++it) {
            int key = it * 32 + skey;
            *(short8*)&Klds[key * LP + sf8] =
                *(const short8*)&kb[((long)(b * T_ + kc + key)) * HS_ + sf8];
        }
        {
            const unsigned short* v0p = &vb[((long)(b * T_ + kc + 2 * vp)) * HS_ + vg * 8];
            short8 v0 = *(const short8*)v0p;
            short8 v1 = *(const short8*)(v0p + HS_);
            #pragma unroll
            for (int j = 0; j < 8; ++j) {
                unsigned pr = (unsigned)(unsigned short)v0[j] |
                              ((unsigned)(unsigned short)v1[j] << 16);
                *(unsigned*)&Vt[(vg * 8 + j) * LP + 2 * vp] = pr;
            }
        }
        __syncthreads();

        floatx4 sv[4];
        #pragma unroll
        for (int kt = 0; kt < 4; ++kt) {
            floatx4 a = {0.f, 0.f, 0.f, 0.f};
            short8 bk0 = *(short8*)&Klds[(kt * 16 + l16) * LP + 0  + quad * 8];
            short8 bk1 = *(short8*)&Klds[(kt * 16 + l16) * LP + 32 + quad * 8];
            a = __builtin_amdgcn_mfma_f32_16x16x32_bf16(aq0, bk0, a, 0, 0, 0);
            a = __builtin_amdgcn_mfma_f32_16x16x32_bf16(aq1, bk1, a, 0, 0, 0);
            sv[kt] = a;
        }

        const bool lastc = (c == qt);
        #pragma unroll
        for (int kt = 0; kt < 4; ++kt) {
            int key = kc + kt * 16 + l16;
            int mk = mask[b * T_ + key];
            #pragma unroll
            for (int r = 0; r < 4; ++r) {
                bool dead = (mk == 0) || (lastc && key > rowg + r);
                if (dead) sv[kt][r] = -INFINITY;
            }
        }

        float alpha[4];
        #pragma unroll
        for (int r = 0; r < 4; ++r) {
            float mx = fmaxf(fmaxf(sv[0][r], sv[1][r]), fmaxf(sv[2][r], sv[3][r]));
            #pragma unroll
            for (int off = 1; off < 16; off <<= 1)
                mx = fmaxf(mx, __shfl_xor(mx, off));
            float mn = fmaxf(m_r[r], mx);
            float a_ = __expf(m_r[r] - mn);
            float ps = 0.f;
            #pragma unroll
            for (int kt = 0; kt < 4; ++kt) {
                float pv = __expf(sv[kt][r] - mn);
                sv[kt][r] = pv;
                ps += pv;
            }
            #pragma unroll
            for (int off = 1; off < 16; off <<= 1)
                ps += __shfl_xor(ps, off);
            l_r[r] = l_r[r] * a_ + ps;
            m_r[r] = mn;
            alpha[r] = a_;
        }
        #pragma unroll
        for (int nt = 0; nt < 4; ++nt)
            #pragma unroll
            for (int r = 0; r < 4; ++r)
                acc_o[nt][r] *= alpha[r];

        unsigned short* pl = Plds[wave];
        #pragma unroll
        for (int kt = 0; kt < 4; ++kt)
            #pragma unroll
            for (int r = 0; r < 4; ++r)
                pl[(quad * 4 + r) * LP + kt * 16 + l16] = f2bf(sv[kt][r]);
        short8 ap0 = *(short8*)&pl[l16 * LP + 0  + quad * 8];
        short8 ap1 = *(short8*)&pl[l16 * LP + 32 + quad * 8];

        #pragma unroll
        for (int nt = 0; nt < 4; ++nt) {
            short8 bv0 = *(short8*)&Vt[(nt * 16 + l16) * LP + 0  + quad * 8];
            short8 bv1 = *(short8*)&Vt[(nt * 16 + l16) * LP + 32 + quad * 8];
            acc_o[nt] = __builtin_amdgcn_mfma_f32_16x16x32_bf16(ap0, bv0, acc_o[nt], 0, 0, 0);
            acc_o[nt] = __builtin_amdgcn_mfma_f32_16x16x32_bf16(ap1, bv1, acc_o[nt], 0, 0, 0);
        }
        __syncthreads();
    }

    // write partials: O unnormalized (bf16), m/l fp32
    unsigned short* Op = Opart + (long)blockIdx.x * 4096;
    #pragma unroll
    for (int nt = 0; nt < 4; ++nt)
        #pragma unroll
        for (int r = 0; r < 4; ++r)
            Op[(wave * 16 + quad * 4 + r) * 64 + nt * 16 + l16] = f2bf(acc_o[nt][r]);
    if (l16 == 0) {
        #pragma unroll
        for (int r = 0; r < 4; ++r) {
            int rl = wave * 16 + quad * 4 + r;
            Mpart[(long)blockIdx.x * 64 + rl] = m_r[r];
            Lpart[(long)blockIdx.x * 64 + rl] = l_r[r];
        }
    }
}

// ---------------------------------------------------------------------------
// Kernel 3b: combine split partials. grid = 8b x 32qt x 2 = 512, block = 256.
// ---------------------------------------------------------------------------
__global__ __launch_bounds__(256) void attn_combine(
    const unsigned short* __restrict__ Opart, const float* __restrict__ Mpart,
    const float* __restrict__ Lpart, float* __restrict__ out)
{
    const int half = blockIdx.x & 1;
    const int bq = blockIdx.x >> 1;
    const int qt = bq & 31;
    const int b  = bq >> 5;
    const int nsp = (qt + 1 < NS) ? qt + 1 : NS;

    const int row  = (threadIdx.x >> 3) + half * 32;   // 0..63
    const int colg = (threadIdx.x & 7) * 8;
    const long base = (long)bq * NS;

    float M = -INFINITY;
    #pragma unroll
    for (int sp = 0; sp < NS; ++sp)
        if (sp < nsp) M = fmaxf(M, Mpart[(base + sp) * 64 + row]);

    float w[NS];
    float L = 0.f;
    #pragma unroll
    for (int sp = 0; sp < NS; ++sp)
        if (sp < nsp) {
            float e = __expf(Mpart[(base + sp) * 64 + row] - M);
            w[sp] = e;
            L += e * Lpart[(base + sp) * 64 + row];
        }

    float acc[8] = {0,0,0,0,0,0,0,0};
    #pragma unroll
    for (int sp = 0; sp < NS; ++sp)
        if (sp < nsp) {
            const unsigned short* Op = Opart + (base + sp) * 4096 + row * 64 + colg;
            short8 o = *(const short8*)Op;
            float ws = w[sp];
            #pragma unroll
            for (int j = 0; j < 8; ++j)
                acc[j] += ws * bf2f((unsigned short)o[j]);
        }

    float inv = 1.0f / L;
    float* op = out + ((long)(b * T_ + qt * 64 + row)) * HS_ + colg;
    floatx4 o0 = { acc[0] * inv, acc[1] * inv, acc[2] * inv, acc[3] * inv };
    floatx4 o1 = { acc[4] * inv, acc[5] * inv, acc[6] * inv, acc[7] * inv };
    *(floatx4*)op = o0;
    *(floatx4*)(op + 4) = o1;
}

// ---------------------------------------------------------------------------
extern "C" void kernel_launch(void* const* d_in, const int* in_sizes, int n_in,
                              void* d_out, int out_size, void* d_ws, size_t ws_size,
                              hipStream_t stream)
{
    const float* qv = (const float*)d_in[0];
    const float* kv = (const float*)d_in[1];
    const float* vv = (const float*)d_in[2];
    const int*   mask = (const int*)d_in[3];
    const float* Wq = (const float*)d_in[4];
    const float* Wk = (const float*)d_in[5];
    const float* Wv = (const float*)d_in[6];
    float* out = (float*)d_out;

    // ws layout: W^T x3 | q/k/v bf16 | O partials bf16 | M,L fp32  (~24.2 MB)
    unsigned short* wt    = (unsigned short*)d_ws;
    unsigned short* qbuf  = wt + 3 * C_ * HS_;
    unsigned short* kbuf  = qbuf + (long)B_ * T_ * HS_;
    unsigned short* vbuf  = kbuf + (long)B_ * T_ * HS_;
    unsigned short* Opart = vbuf + (long)B_ * T_ * HS_;
    float* Mpart = (float*)(Opart + (long)B_ * 32 * NS * 4096);
    float* Lpart = Mpart + (long)B_ * 32 * NS * 64;

    prep_wt<<<48, 256, 0, stream>>>(Wq, Wk, Wv, wt);
    proj_kernel<<<768, 256, 0, stream>>>(qv, kv, vv, wt, qbuf, kbuf, vbuf);
    attn_partial<<<B_ * 32 * NS, 256, 0, stream>>>(qbuf, kbuf, vbuf, mask, Opart, Mpart, Lpart);
    attn_combine<<<B_ * 32 * 2, 256, 0, stream>>>(Opart, Mpart, Lpart, out);
}